// Round 5
// baseline (3884.246 us; speedup 1.0000x reference)
//
#include <hip/hip_runtime.h>

// SPDReLU via matrix-sign (Polar Express 8-step), PURE-VALU certainty round.
//   relu_spd(P) = (P + P*sign(P))/2  (differs from eigh-clamp by <= 1e-4).
// R5: R4 still failed (absmax 4.8) with a provably-robust MFMA construction,
// so this round eliminates the last unverifiable premises (gfx950 16x16x32
// A/B fragment k-mappings) by doing the 16x16 matmuls on the VALU with
// __shfl (ds_bpermute) + fmaf only. Full fp32 => zero bf16 eigenvalue noise
// => the original tight-margin PE-8 schedule is safe (margin 3e-3 >> 1e-6).
// One wave per matrix; lane (g=lane>>4, c=lane&15) owns M[4g+r][c], r=0..3.

__device__ __forceinline__ void mm16(const float a[4], const float b[4],
                                     float d[4], int c, int g) {
  // d[r] = (A*B)[4g+r][c] = sum_k A[4g+r][k] * B[k][c]
  d[0] = 0.f; d[1] = 0.f; d[2] = 0.f; d[3] = 0.f;
#pragma unroll
  for (int k = 0; k < 16; ++k) {
    // B[k][c] lives in reg (k&3) of lane (c + 16*(k>>2))
    float bk = __shfl(b[k & 3], c + ((k >> 2) << 4), 64);
#pragma unroll
    for (int r = 0; r < 4; ++r) {
      // A[4g+r][k] lives in reg r of lane (k + 16*g)
      float ak = __shfl(a[r], (g << 4) + k, 64);
      d[r] = fmaf(ak, bk, d[r]);
    }
  }
}

__global__ __launch_bounds__(256) void spdrelu_valu(
    const float* __restrict__ P, float* __restrict__ OUT, int nmat) {
  const int lane = threadIdx.x & 63;
  const int wid  = threadIdx.x >> 6;
  const int mat  = blockIdx.x * 4 + wid;
  if (mat >= nmat) return;

  const int c = lane & 15;
  const int g = lane >> 4;

  const float* Pm = P + (size_t)mat * 256;
  float p[4], x[4];
#pragma unroll
  for (int r = 0; r < 4; ++r) p[r] = Pm[(4 * g + r) * 16 + c];

  // ---- per-matrix Frobenius norm: ||P||_2 <= ||P||_F for any input ----
  float nrm = p[0] * p[0] + p[1] * p[1] + p[2] * p[2] + p[3] * p[3];
#pragma unroll
  for (int off = 32; off; off >>= 1) nrm += __shfl_xor(nrm, off, 64);
  const float inv = 0.97f * rsqrtf(fmaxf(nrm, 1e-30f));
#pragma unroll
  for (int r = 0; r < 4; ++r) x[r] = p[r] * inv;

  // ---- Polar Express 8-step quintic schedule (fp32-exact is in-margin) ----
  const float Ak[8] = {8.28721201814563f,  4.107059111542203f,
                       3.9486908534822946f, 3.3184196573706015f,
                       2.300652019954817f,  1.891301407787398f,
                       1.8750014808534479f, 1.875f};
  const float Bk[8] = {-23.595886519098837f, -2.9478499167379106f,
                       -2.908902115962949f,  -2.488488024314874f,
                       -1.6689039845747493f, -1.2679958271945868f,
                       -1.2500016453999487f, -1.25f};
  const float Ck[8] = {17.300387312530933f, 0.5448431082926601f,
                       0.5518191394370137f, 0.51004894012372f,
                       0.4188073119525673f, 0.37680408948524835f,
                       0.3750001645474248f, 0.375f};

#pragma unroll
  for (int it = 0; it < 8; ++it) {
    float y[4], y2[4], w[4], xw[4];
    mm16(x, x, y, c, g);    // Y  = X^2
    mm16(y, y, y2, c, g);   // Y2 = X^4
#pragma unroll
    for (int r = 0; r < 4; ++r) w[r] = Bk[it] * y[r] + Ck[it] * y2[r];
    mm16(x, w, xw, c, g);   // X*(b*Y + c*Y2) = b*X^3 + c*X^5
#pragma unroll
    for (int r = 0; r < 4; ++r) x[r] = Ak[it] * x[r] + xw[r];
  }

  // ---- out = (P + P*S)/2, all fp32 ----
  float ps[4];
  mm16(p, x, ps, c, g);
  float* Om = OUT + (size_t)mat * 256;
#pragma unroll
  for (int r = 0; r < 4; ++r)
    Om[(4 * g + r) * 16 + c] = 0.5f * (p[r] + ps[r]);
}

extern "C" void kernel_launch(void* const* d_in, const int* in_sizes, int n_in,
                              void* d_out, int out_size, void* d_ws,
                              size_t ws_size, hipStream_t stream) {
  (void)n_in; (void)out_size; (void)d_ws; (void)ws_size;
  const float* P = (const float*)d_in[0];
  float* OUT = (float*)d_out;
  const int nmat = in_sizes[0] / 256;
  const int blocks = (nmat + 3) / 4;  // 4 waves = 4 matrices per block
  spdrelu_valu<<<dim3(blocks), dim3(256), 0, stream>>>(P, OUT, nmat);
}